// Round 6
// baseline (336.638 us; speedup 1.0000x reference)
//
#include <hip/hip_runtime.h>
#include <hip/hip_bf16.h>
#include <cstddef>
#include <cstdint>

#define DM 512
#define DS 64
#define L_SEQ 8192
#define NB 8
#define M_ROWS (NB * L_SEQ)      // 65536
#define LN_EPS 1e-3f
#define NCHUNK 256
#define LCH 32                   // NCHUNK * LCH == L_SEQ

typedef __attribute__((ext_vector_type(8))) short short8;
typedef __attribute__((ext_vector_type(4))) float f32x4;
using bf16 = __hip_bfloat16;

__device__ __forceinline__ unsigned short f2bf(float f) {
    bf16 h = __float2bfloat16(f);
    return *reinterpret_cast<unsigned short*>(&h);
}

// Pre-swizzle (element space): XOR 16B-granule low-2-bits with (row>>1)&3.
// Stays within each 32-element group -> compatible with BK=32 K-slicing.
// Bank math: fragment ds_read_b128 lands exactly 2 lanes/bank (free).
__device__ __forceinline__ int swzcol(int row, int col) {
    return col ^ ((((row >> 1) & 3)) << 3);
}

__device__ __forceinline__ void gload_lds16(const void* g, void* l) {
    __builtin_amdgcn_global_load_lds(
        (const __attribute__((address_space(1))) void*)g,
        (__attribute__((address_space(3))) void*)l, 16, 0, 0);
}

template<int N> __device__ __forceinline__ void wait_vm() {
    static_assert(N == 0 || N == 1 || N == 2, "");
    if constexpr (N == 0)      asm volatile("s_waitcnt vmcnt(0)" ::: "memory");
    else if constexpr (N == 1) asm volatile("s_waitcnt vmcnt(1)" ::: "memory");
    else                       asm volatile("s_waitcnt vmcnt(2)" ::: "memory");
}

__device__ __forceinline__ void block_barrier() {
    asm volatile("" ::: "memory");
    __builtin_amdgcn_s_barrier();
    asm volatile("" ::: "memory");
}

// ---------------- weight transpose + bf16 convert + pre-swizzle ----------------
__global__ __launch_bounds__(256) void wtrans_all(const float* __restrict__ W_in,
                                                  const float* __restrict__ W_xs,
                                                  const float* __restrict__ W_so,
                                                  const float* __restrict__ W_out,
                                                  unsigned short* __restrict__ WinT,
                                                  unsigned short* __restrict__ WxsT,
                                                  unsigned short* __restrict__ WsoT,
                                                  unsigned short* __restrict__ WoutT)
{
    int i = blockIdx.x * 256 + threadIdx.x;
    if (i < 262144) {                       // W_in 512x512 -> WinT[n][k]
        int k = i >> 9, n = i & 511;
        WinT[n * 512 + swzcol(n, k)] = f2bf(W_in[i]);
    } else if (i < 294912) {                // W_xs 512x64 -> WxsT[n<64][k<512]
        int j = i - 262144; int k = j >> 6, n = j & 63;
        WxsT[n * 512 + swzcol(n, k)] = f2bf(W_xs[j]);
    } else if (i < 327680) {                // W_so 64x512 -> WsoT[n<512][k<64]
        int j = i - 294912; int k = j >> 9, n = j & 511;
        WsoT[n * 64 + swzcol(n, k)] = f2bf(W_so[j]);
    } else if (i < 589824) {                // W_out 512x512 -> WoutT[n][k]
        int j = i - 327680; int k = j >> 9, n = j & 511;
        WoutT[n * 512 + swzcol(n, k)] = f2bf(W_out[j]);
    }
}

// ---------------- LayerNorm: one wave per row, pre-swizzled bf16 out -----------
__global__ __launch_bounds__(64) void ln_kernel(const float* __restrict__ x,
                                                const float* __restrict__ gamma,
                                                const float* __restrict__ beta,
                                                unsigned short* __restrict__ xn)
{
    size_t row = blockIdx.x;
    int lane = threadIdx.x;                       // covers cols lane*8..+7
    const float4* xr = (const float4*)(x + row * DM);
    float4 v0 = xr[lane * 2];
    float4 v1 = xr[lane * 2 + 1];
    float s  = v0.x + v0.y + v0.z + v0.w + v1.x + v1.y + v1.z + v1.w;
    float s2 = v0.x*v0.x + v0.y*v0.y + v0.z*v0.z + v0.w*v0.w
             + v1.x*v1.x + v1.y*v1.y + v1.z*v1.z + v1.w*v1.w;
    #pragma unroll
    for (int off = 32; off > 0; off >>= 1) {
        s  += __shfl_xor(s,  off);
        s2 += __shfl_xor(s2, off);
    }
    float mu  = s * (1.0f / DM);
    float var = s2 * (1.0f / DM) - mu * mu;
    float rs  = rsqrtf(var + LN_EPS);
    const float4* g4 = (const float4*)gamma;
    const float4* b4 = (const float4*)beta;
    float4 g0 = g4[lane * 2], g1 = g4[lane * 2 + 1];
    float4 bb0 = b4[lane * 2], bb1 = b4[lane * 2 + 1];
    short8 o;
    o[0] = (short)f2bf((v0.x - mu) * rs * g0.x + bb0.x);
    o[1] = (short)f2bf((v0.y - mu) * rs * g0.y + bb0.y);
    o[2] = (short)f2bf((v0.z - mu) * rs * g0.z + bb0.z);
    o[3] = (short)f2bf((v0.w - mu) * rs * g0.w + bb0.w);
    o[4] = (short)f2bf((v1.x - mu) * rs * g1.x + bb1.x);
    o[5] = (short)f2bf((v1.y - mu) * rs * g1.y + bb1.y);
    o[6] = (short)f2bf((v1.z - mu) * rs * g1.z + bb1.z);
    o[7] = (short)f2bf((v1.w - mu) * rs * g1.w + bb1.w);
    int key = ((int)row >> 1) & 3;
    *(short8*)(xn + row * DM + (size_t)((lane ^ key) * 8)) = o;
}

// ---------------- epilogue helpers ----------------
__device__ __forceinline__ float aux_to_float(float x) { return x; }
__device__ __forceinline__ float aux_to_float(bf16 x)  { return __bfloat162float(x); }
__device__ __forceinline__ void store_out(float* C, size_t i, float v) { C[i] = v; }
__device__ __forceinline__ void store_out(bf16* C, size_t i, float v)  { C[i] = __float2bfloat16(v); }

// ---------------- 3-buffer deep-pipelined MFMA GEMM (T3+T4, prefetch dist 2) ----
// C = A(MxK) @ BT^T (BT is NxK) + epilogue. A, BT pre-swizzled bf16.
// BM=128, BK=32, 512 threads (8 waves, WR x WC), 3 LDS buffers,
// ONE barrier per K-step, counted vmcnt (2 tiles always in flight).
template<int BN, int WR, int WC, typename OutT, typename AuxT,
         bool HB, bool HA, bool HS, bool SWZO, bool AUXSWZ>
__global__ __launch_bounds__(512, 6) void gemm_pipe(const unsigned short* __restrict__ A,
                                                    const unsigned short* __restrict__ BT,
                                                    const float* __restrict__ bias,
                                                    const AuxT* __restrict__ aux,
                                                    const float* __restrict__ scale,
                                                    OutT* __restrict__ C,
                                                    int M, int N, int K)
{
    constexpr int BM = 128;
    constexpr int MF = BM / (16 * WR), NF = BN / (16 * WC);
    constexpr int ABYTES = BM * 64;           // BK=32 -> 64 B/row = 8 KB
    constexpr int BBYTES = BN * 64;
    constexpr bool BH = (BN == 64);           // B staged by waves 0..3 only
    __shared__ unsigned char LDS[3][ABYTES + BBYTES];

    const int tid = threadIdx.x;
    const int lane = tid & 63, w = tid >> 6;
    const int fr = lane & 15, fq = lane >> 4;
    const int wr = w % WR, wc = w / WR;

    // XCD-aware bijective swizzle (T1), N-fastest (gridDim.x % 8 == 0)
    const int ny = N / BN;
    const int per = (int)gridDim.x >> 3;
    const int lg = ((int)blockIdx.x & 7) * per + ((int)blockIdx.x >> 3);
    const size_t bm0 = (size_t)(lg / ny) * BM;
    const int bn0 = (lg % ny) * BN;
    const int nk = K / 32;

    f32x4 acc[MF][NF];
    #pragma unroll
    for (int m = 0; m < MF; ++m)
        #pragma unroll
        for (int n = 0; n < NF; ++n)
            acc[m][n] = (f32x4){0.f, 0.f, 0.f, 0.f};

    auto stage = [&](int buf, int t) {
        // A: one 8 KB instr (512 thr x 16 B); LDS linear = wave base + lane*16
        int row = tid >> 2;                       // 0..127
        gload_lds16(A + (bm0 + row) * (size_t)K + t * 32 + (tid & 3) * 8,
                    &LDS[buf][w * 1024]);
        if constexpr (!BH) {
            gload_lds16(BT + (size_t)(bn0 + row) * K + t * 32 + (tid & 3) * 8,
                        &LDS[buf][ABYTES + w * 1024]);
        } else {
            if (w < 4)                            // rows 0..63
                gload_lds16(BT + (size_t)(bn0 + row) * K + t * 32 + (tid & 3) * 8,
                            &LDS[buf][ABYTES + w * 1024]);
        }
    };

    auto compute = [&](int buf) {
        short8 af[MF], bfr[NF];
        #pragma unroll
        for (int m = 0; m < MF; ++m) {
            int row = wr * (BM / WR) + m * 16 + fr;
            int g = fq ^ ((row >> 1) & 3);
            af[m] = *(const short8*)&LDS[buf][row * 64 + g * 16];
        }
        #pragma unroll
        for (int n = 0; n < NF; ++n) {
            int col = wc * (BN / WC) + n * 16 + fr;
            int g = fq ^ ((col >> 1) & 3);
            bfr[n] = *(const short8*)&LDS[buf][ABYTES + col * 64 + g * 16];
        }
        #pragma unroll
        for (int m = 0; m < MF; ++m)
            #pragma unroll
            for (int n = 0; n < NF; ++n)
                acc[m][n] = __builtin_amdgcn_mfma_f32_16x16x32_bf16(af[m], bfr[n], acc[m][n], 0, 0, 0);
    };

    // prologue: 2 tiles in flight
    stage(0, 0);
    stage(1, 1);
    for (int t = 0; t < nk; ++t) {
        if (t == nk - 1) {
            wait_vm<0>();
        } else {
            if (BH && w >= 4) wait_vm<1>();
            else              wait_vm<2>();
        }
        block_barrier();                 // tile t visible to all; buf (t-1)%3 free
        compute(t % 3);
        if (t + 2 < nk) stage((t + 2) % 3, t + 2);
    }

    // epilogue (aux read inline; 3 blocks/CU hide its latency)
    #pragma unroll
    for (int n = 0; n < NF; ++n) {
        int coll = wc * (BN / WC) + n * 16 + fr;
        int colg = bn0 + coll;
        float bv = HB ? bias[colg] : 0.f;
        float sv = HS ? scale[colg] : 1.f;
        #pragma unroll
        for (int m = 0; m < MF; ++m) {
            int rowl = wr * (BM / WR) + m * 16 + fq * 4;
            #pragma unroll
            for (int r = 0; r < 4; ++r) {
                size_t row = bm0 + rowl + r;
                float v = acc[m][n][r] + bv;
                if constexpr (HA) {
                    size_t ac = AUXSWZ ? (size_t)swzcol(rowl + r, colg) : (size_t)colg;
                    v += sv * aux_to_float(aux[row * (size_t)N + ac]);
                }
                size_t oc = SWZO ? (size_t)swzcol(rowl + r, colg) : (size_t)colg;
                store_out(C, row * (size_t)N + oc, v);
            }
        }
    }
}

// ---------------- SSM scan (chunked, 3 passes) ----------------
__device__ __forceinline__ void ssm_params(const float* A_log, const float* log_delta,
                                           const float* Bv, int n, float& Ab, float& Bb)
{
    float A  = -expf(A_log[n]);
    float dl = log1pf(expf(log_delta[n]));   // softplus
    float dA2 = dl * A * 0.5f;
    float inv = 1.0f / (1.0f - dA2);
    Ab = (1.0f + dA2) * inv;
    Bb = dl * inv * Bv[n];
}

__global__ __launch_bounds__(64) void scan_pass1(const float* __restrict__ xs,
                                                 const float* __restrict__ A_log,
                                                 const float* __restrict__ log_delta,
                                                 const float* __restrict__ Bv,
                                                 float* __restrict__ carry)
{
    int b = blockIdx.x / NCHUNK;
    int c = blockIdx.x % NCHUNK;
    int n = threadIdx.x;
    float Ab, Bb;
    ssm_params(A_log, log_delta, Bv, n, Ab, Bb);
    size_t base = ((size_t)b * L_SEQ + (size_t)c * LCH) * DS + n;
    float h = 0.0f;
    for (int t = 0; t < LCH; ++t)
        h = Ab * h + Bb * xs[base + (size_t)t * DS];
    carry[((size_t)b * NCHUNK + c) * DS + n] = h;
}

__global__ __launch_bounds__(64) void scan_pass2(const float* __restrict__ A_log,
                                                 const float* __restrict__ log_delta,
                                                 const float* __restrict__ Bv,
                                                 const float* __restrict__ carry,
                                                 float* __restrict__ hin)
{
    int b = blockIdx.x;
    int n = threadIdx.x;
    float Ab, Bb;
    ssm_params(A_log, log_delta, Bv, n, Ab, Bb);
    float powA = powf(Ab, (float)LCH);
    float h = 0.0f;
    for (int c = 0; c < NCHUNK; ++c) {
        size_t idx = ((size_t)b * NCHUNK + c) * DS + n;
        hin[idx] = h;
        h = powA * h + carry[idx];
    }
}

// ys written PRE-SWIZZLED (A-operand of G7): col = n ^ (((t>>1)&3)<<3)
__global__ __launch_bounds__(64) void scan_pass3(const float* __restrict__ xs,
                                                 const float* __restrict__ A_log,
                                                 const float* __restrict__ log_delta,
                                                 const float* __restrict__ Bv,
                                                 const float* __restrict__ Cv,
                                                 const float* __restrict__ hin,
                                                 unsigned short* __restrict__ ys)
{
    int b = blockIdx.x / NCHUNK;
    int c = blockIdx.x % NCHUNK;
    int n = threadIdx.x;
    float Ab, Bb;
    ssm_params(A_log, log_delta, Bv, n, Ab, Bb);
    float Cn = Cv[n];
    size_t base = ((size_t)b * L_SEQ + (size_t)c * LCH) * DS + n;
    size_t rowbase = ((size_t)b * L_SEQ + (size_t)c * LCH) * DS;
    float h = hin[((size_t)b * NCHUNK + c) * DS + n];
    for (int t = 0; t < LCH; ++t) {
        h = Ab * h + Bb * xs[base + (size_t)t * DS];
        int col = n ^ (((t >> 1) & 3) << 3);      // (rowbase rows are %32==0)
        ys[rowbase + (size_t)t * DS + col] = f2bf(Cn * h);
    }
}

// ---------------- launcher ----------------
extern "C" void kernel_launch(void* const* d_in, const int* in_sizes, int n_in,
                              void* d_out, int out_size, void* d_ws, size_t ws_size,
                              hipStream_t stream)
{
    const float* x         = (const float*)d_in[0];
    const float* ln_gamma  = (const float*)d_in[1];
    const float* ln_beta   = (const float*)d_in[2];
    const float* W_in      = (const float*)d_in[3];
    const float* b_in      = (const float*)d_in[4];
    const float* W_xs      = (const float*)d_in[5];
    const float* A_log     = (const float*)d_in[6];
    const float* log_delta = (const float*)d_in[7];
    const float* Bv        = (const float*)d_in[8];
    const float* Cv        = (const float*)d_in[9];
    const float* Dv        = (const float*)d_in[10];
    const float* W_so      = (const float*)d_in[11];
    const float* W_out     = (const float*)d_in[12];
    const float* b_out     = (const float*)d_in[13];
    float* out = (float*)d_out;

    const size_t M = M_ROWS;
    float*          xs_f = (float*)d_ws;                      // M*64 f32
    unsigned short* xn_b = (unsigned short*)(xs_f + M * DS);  // M*512 bf16 (reused as t1)
    unsigned short* z_b  = xn_b + M * (size_t)DM;             // M*512 bf16
    unsigned short* ys_b = z_b + M * (size_t)DM;              // M*64 bf16
    unsigned short* WinT = ys_b + M * (size_t)DS;             // 512*512
    unsigned short* WxsT = WinT + (size_t)DM * DM;            // 64*512
    unsigned short* WsoT = WxsT + (size_t)DS * DM;            // 512*64
    unsigned short* WoutT= WsoT + (size_t)DM * DS;            // 512*512
    float* carry = (float*)(WoutT + (size_t)DM * DM);         // 8*256*64
    float* hin   = carry + NB * NCHUNK * DS;                  // 8*256*64
    unsigned short* t1_b = xn_b;                              // xn dead after G2

    wtrans_all<<<dim3(589824 / 256), dim3(256), 0, stream>>>(W_in, W_xs, W_so, W_out,
                                                             WinT, WxsT, WsoT, WoutT);
    // LN -> xn (pre-swizzled bf16)
    ln_kernel<<<dim3((unsigned)M), dim3(64), 0, stream>>>(x, ln_gamma, ln_beta, xn_b);
    // G2: z = xn @ W_in + b_in   (bf16, pre-swizzled out)
    gemm_pipe<128, 2, 4, bf16, float, true, false, false, true, false>
        <<<dim3((M / 128) * (DM / 128)), dim3(512), 0, stream>>>(xn_b, WinT, b_in, nullptr, nullptr,
                                                                 (bf16*)z_b, (int)M, DM, DM);
    // G3: xs = z @ W_xs          (f32 out, plain)
    gemm_pipe<64, 4, 2, float, float, false, false, false, false, false>
        <<<dim3(M / 128), dim3(512), 0, stream>>>(z_b, WxsT, nullptr, nullptr, nullptr,
                                                  xs_f, (int)M, DS, DM);
    // scan
    scan_pass1<<<dim3(NB * NCHUNK), dim3(64), 0, stream>>>(xs_f, A_log, log_delta, Bv, carry);
    scan_pass2<<<dim3(NB), dim3(64), 0, stream>>>(A_log, log_delta, Bv, carry, hin);
    scan_pass3<<<dim3(NB * NCHUNK), dim3(64), 0, stream>>>(xs_f, A_log, log_delta, Bv, Cv, hin, ys_b);
    // G7: t1 = ys @ W_so + D*z   (K=64 -> nk=2; bf16 pre-swizzled out; z aux de-swizzled)
    gemm_pipe<128, 2, 4, bf16, bf16, false, true, true, true, true>
        <<<dim3((M / 128) * (DM / 128)), dim3(512), 0, stream>>>(ys_b, WsoT, nullptr, (const bf16*)z_b,
                                                                 Dv, (bf16*)t1_b, (int)M, DM, DS);
    // G8: out = t1 @ W_out + b_out + x  (f32 out, plain)
    gemm_pipe<128, 2, 4, float, float, true, true, false, false, false>
        <<<dim3((M / 128) * (DM / 128)), dim3(512), 0, stream>>>(t1_b, WoutT, b_out, x, nullptr,
                                                                 out, (int)M, DM, DM);
}

// Round 7
// 258.976 us; speedup vs baseline: 1.2999x; 1.2999x over previous
//
#include <hip/hip_runtime.h>
#include <hip/hip_bf16.h>
#include <cstddef>
#include <cstdint>

#define DM 512
#define DS 64
#define L_SEQ 8192
#define NB 8
#define M_ROWS (NB * L_SEQ)      // 65536
#define LN_EPS 1e-3f
#define NCHUNK 256
#define LCH 32                   // NCHUNK * LCH == L_SEQ

typedef __attribute__((ext_vector_type(8))) short short8;
typedef __attribute__((ext_vector_type(4))) float f32x4;
using bf16 = __hip_bfloat16;
using ushort_t = unsigned short;

__device__ __forceinline__ unsigned short f2bf(float f) {
    bf16 h = __float2bfloat16(f);
    return *reinterpret_cast<unsigned short*>(&h);
}

// Pre-swizzle column map for A-operands (rule #21: linear global_load_lds +
// swizzle applied at produce time + matching swizzled ds_read):
// within each 64-elem (128B) row segment, 8-elem granule g -> g ^ (row&7).
__device__ __forceinline__ int swzcol(int row, int col) {
    return (col & ~63) | (((((col >> 3) & 7) ^ (row & 7))) << 3) | (col & 7);
}

// B-operand MFMA fragment packing: element (k, n) of a KxN weight ->
// pk[((n16*Kd32 + kt)*64 + fq*16 + fr)*8 + e]; one wave fragment = 1 KB contig.
__device__ __forceinline__ size_t pkidx(int k, int n, int Kd32) {
    int n16 = n >> 4, fr = n & 15, kt = k >> 5, fq = (k >> 3) & 3, e = k & 7;
    return (((size_t)(n16 * Kd32 + kt) * 64 + fq * 16 + fr) << 3) + e;
}

__device__ __forceinline__ void gload_lds16(const void* g, void* l) {
    __builtin_amdgcn_global_load_lds(
        (const __attribute__((address_space(1))) void*)g,
        (__attribute__((address_space(3))) void*)l, 16, 0, 0);
}

template<int N> __device__ __forceinline__ void wait_vm() {
    static_assert(N == 0 || N == 6, "");
    if constexpr (N == 0) asm volatile("s_waitcnt vmcnt(0)" ::: "memory");
    else                  asm volatile("s_waitcnt vmcnt(6)" ::: "memory");
}

__device__ __forceinline__ void block_barrier() {
    asm volatile("" ::: "memory");
    __builtin_amdgcn_s_barrier();
    asm volatile("" ::: "memory");
}

// ---------------- prep: tiny weight-product GEMMs (fp32) ----------------
// sWsoOut[s][j] = sum_c W_so[s][c]*W_out[c][j]   (64x512)
// sWinxs[k][n]  = sum_c W_in[k][c]*W_xs[c][n]    (512x64)
// sBxs[n]       = sum_c b_in[c]*W_xs[c][n]       (64)
__global__ __launch_bounds__(256) void prep(const float* __restrict__ W_so,
                                            const float* __restrict__ W_out,
                                            const float* __restrict__ W_in,
                                            const float* __restrict__ W_xs,
                                            const float* __restrict__ b_in,
                                            float* __restrict__ sWsoOut,
                                            float* __restrict__ sWinxs,
                                            float* __restrict__ sBxs)
{
    int i = blockIdx.x * 256 + threadIdx.x;
    if (i < 32768) {
        int s = i >> 9, j = i & 511;
        float a = 0.f;
        for (int c = 0; c < 512; ++c) a += W_so[s * 512 + c] * W_out[c * 512 + j];
        sWsoOut[i] = a;
    } else if (i < 65536) {
        int idx = i - 32768; int k = idx >> 6, n = idx & 63;
        float a = 0.f;
        for (int c = 0; c < 512; ++c) a += W_in[k * 512 + c] * W_xs[c * 64 + n];
        sWinxs[idx] = a;
    } else if (i < 65600) {
        int n = i - 65536;
        float a = 0.f;
        for (int c = 0; c < 512; ++c) a += b_in[c] * W_xs[c * 64 + n];
        sBxs[n] = a;
    }
}

// ---------------- pack weights into fragment order (bf16) ----------------
__global__ __launch_bounds__(256) void pack_all(const float* __restrict__ W_in,
                                                const float* __restrict__ sWinxs,
                                                const float* __restrict__ sWsoOut,
                                                const float* __restrict__ W_out,
                                                const float* __restrict__ Dv,
                                                ushort_t* __restrict__ WinPk,
                                                ushort_t* __restrict__ WinxsPk,
                                                ushort_t* __restrict__ WsooutPk,
                                                ushort_t* __restrict__ WdoutPk)
{
    int i = blockIdx.x * 256 + threadIdx.x;
    if (i < 262144) {                 // W_in: B[k][n], K=512,N=512
        int k = i >> 9, n = i & 511;
        WinPk[pkidx(k, n, 16)] = f2bf(W_in[i]);
    } else if (i < 294912) {          // Winxs: B[k][n<64], K=512
        int j = i - 262144; int k = j >> 6, n = j & 63;
        WinxsPk[pkidx(k, n, 16)] = f2bf(sWinxs[j]);
    } else if (i < 327680) {          // WsoOut: B[k=s<64][n<512], K=64 -> Kd32=2
        int j = i - 294912; int s = j >> 9, n = j & 511;
        WsooutPk[pkidx(s, n, 2)] = f2bf(sWsoOut[j]);
    } else if (i < 589824) {          // WD_out: B[k=c][n] = D[c]*W_out[c][n], K=512
        int j = i - 327680; int c = j >> 9, n = j & 511;
        WdoutPk[pkidx(c, n, 16)] = f2bf(Dv[c] * W_out[j]);
    }
}

// ---------------- LayerNorm: one wave per row, pre-swizzled bf16 out -----------
__global__ __launch_bounds__(64) void ln_kernel(const float* __restrict__ x,
                                                const float* __restrict__ gamma,
                                                const float* __restrict__ beta,
                                                ushort_t* __restrict__ xn)
{
    size_t row = blockIdx.x;
    int lane = threadIdx.x;
    const float4* xr = (const float4*)(x + row * DM);
    float4 v0 = xr[lane * 2];
    float4 v1 = xr[lane * 2 + 1];
    float s  = v0.x + v0.y + v0.z + v0.w + v1.x + v1.y + v1.z + v1.w;
    float s2 = v0.x*v0.x + v0.y*v0.y + v0.z*v0.z + v0.w*v0.w
             + v1.x*v1.x + v1.y*v1.y + v1.z*v1.z + v1.w*v1.w;
    #pragma unroll
    for (int off = 32; off > 0; off >>= 1) {
        s  += __shfl_xor(s,  off);
        s2 += __shfl_xor(s2, off);
    }
    float mu  = s * (1.0f / DM);
    float var = s2 * (1.0f / DM) - mu * mu;
    float rs  = rsqrtf(var + LN_EPS);
    const float4* g4 = (const float4*)gamma;
    const float4* b4 = (const float4*)beta;
    float4 g0 = g4[lane * 2], g1 = g4[lane * 2 + 1];
    float4 bb0 = b4[lane * 2], bb1 = b4[lane * 2 + 1];
    short8 o;
    o[0] = (short)f2bf((v0.x - mu) * rs * g0.x + bb0.x);
    o[1] = (short)f2bf((v0.y - mu) * rs * g0.y + bb0.y);
    o[2] = (short)f2bf((v0.z - mu) * rs * g0.z + bb0.z);
    o[3] = (short)f2bf((v0.w - mu) * rs * g0.w + bb0.w);
    o[4] = (short)f2bf((v1.x - mu) * rs * g1.x + bb1.x);
    o[5] = (short)f2bf((v1.y - mu) * rs * g1.y + bb1.y);
    o[6] = (short)f2bf((v1.z - mu) * rs * g1.z + bb1.z);
    o[7] = (short)f2bf((v1.w - mu) * rs * g1.w + bb1.w);
    int g = (lane & 7) ^ ((int)row & 7);          // swizzled granule
    *(short8*)(xn + row * DM + (lane >> 3) * 64 + g * 8) = o;
}

// ---------------- epilogue helpers ----------------
__device__ __forceinline__ void store_out(float* C, size_t i, float v) { C[i] = v; }
__device__ __forceinline__ void store_out(bf16* C, size_t i, float v)  { C[i] = __float2bfloat16(v); }

// ---------------- MFMA GEMM: A via LDS (counted vmcnt dbuf), B via packed-global
// -> registers (ping-pong, 1 step ahead). Optionally dual-pair (GD kernel):
// t==0: (A1,B1,K=64), t>=1: (A2,B2,K=K2). BM=128, BK=64, 512 thr (8 waves WRxWC).
template<int BN, int WR, int WC, typename OutT, bool DUAL, bool HB, bool HA, bool SWZO>
__global__ __launch_bounds__(512, 4) void gemm_bp(const ushort_t* __restrict__ A1,
                                                  const ushort_t* __restrict__ B1,
                                                  const ushort_t* __restrict__ A2,
                                                  const ushort_t* __restrict__ B2,
                                                  const float* __restrict__ bias,
                                                  const float* __restrict__ aux,
                                                  OutT* __restrict__ C,
                                                  int M, int N, int K2)
{
    constexpr int BM = 128;
    constexpr int MF = BM / (16 * WR), NF = BN / (16 * WC);
    static_assert(NF == 2, "b ping-pong arrays assume NF==2");
    __shared__ unsigned char LDS[2][BM * 128];    // 32 KB total

    const int tid = threadIdx.x;
    const int lane = tid & 63, w = tid >> 6;
    const int fr = lane & 15, fq = lane >> 4;
    const int wr = w % WR, wc = w / WR;

    // XCD-aware bijective swizzle (T1), N-fastest (gridDim.x % 8 == 0)
    const int ny = N / BN;
    const int per = (int)gridDim.x >> 3;
    const int lg = ((int)blockIdx.x & 7) * per + ((int)blockIdx.x >> 3);
    const size_t bm0 = (size_t)(lg / ny) * BM;
    const int bn0 = (lg % ny) * BN;
    const int nk = (DUAL ? 1 : 0) + K2 / 64;

    f32x4 acc[MF][NF];
    #pragma unroll
    for (int m = 0; m < MF; ++m)
        #pragma unroll
        for (int n = 0; n < NF; ++n)
            acc[m][n] = (f32x4){0.f, 0.f, 0.f, 0.f};

    auto stage = [&](int buf, int t) {
        #pragma unroll
        for (int j = 0; j < 2; ++j) {
            int r = j * 64 + (tid >> 3);
            const ushort_t* src;
            if constexpr (DUAL) {
                if (t == 0) src = A1 + (bm0 + r) * (size_t)64 + (tid & 7) * 8;
                else        src = A2 + (bm0 + r) * (size_t)512 + (size_t)(t - 1) * 64 + (tid & 7) * 8;
            } else {
                src = A2 + (bm0 + r) * (size_t)K2 + (size_t)t * 64 + (tid & 7) * 8;
            }
            gload_lds16(src, &LDS[buf][j * 8192 + w * 1024]);
        }
    };

    auto loadB = [&](short8 (&bb)[2][2], int t) {
        #pragma unroll
        for (int h = 0; h < 2; ++h)
            #pragma unroll
            for (int n = 0; n < NF; ++n) {
                int n16g = (bn0 + wc * (BN / WC) + n * 16) >> 4;
                const ushort_t* p;
                if constexpr (DUAL) {
                    if (t == 0) p = B1 + (((size_t)(n16g * 2 + h) * 64 + lane) << 3);
                    else        p = B2 + (((size_t)(n16g * 16 + (t - 1) * 2 + h) * 64 + lane) << 3);
                } else {
                    p = B2 + (((size_t)(n16g * (K2 / 32) + t * 2 + h) * 64 + lane) << 3);
                }
                bb[h][n] = *(const short8*)p;
            }
    };

    auto compute = [&](int buf, const short8 (&bb)[2][2]) {
        #pragma unroll
        for (int h = 0; h < 2; ++h) {
            short8 af[MF];
            #pragma unroll
            for (int m = 0; m < MF; ++m) {
                int row = wr * (BM / WR) + m * 16 + fr;
                int g = (h * 4 + fq) ^ (row & 7);
                af[m] = *(const short8*)&LDS[buf][row * 128 + g * 16];
            }
            #pragma unroll
            for (int m = 0; m < MF; ++m)
                #pragma unroll
                for (int n = 0; n < NF; ++n)
                    acc[m][n] = __builtin_amdgcn_mfma_f32_16x16x32_bf16(af[m], bb[h][n], acc[m][n], 0, 0, 0);
        }
    };

    short8 bX[2][2], bY[2][2];
    stage(0, 0);
    loadB(bX, 0);
    int buf = 0;
    for (int t = 0; t < nk; t += 2) {
        // even step t (uses bX)
        if (t + 1 < nk) { stage(buf ^ 1, t + 1); loadB(bY, t + 1); }
        __builtin_amdgcn_sched_barrier(0);
        if (t + 1 < nk) wait_vm<6>(); else wait_vm<0>();
        block_barrier();
        compute(buf, bX);
        if (t + 1 < nk) {
            block_barrier();
            buf ^= 1;
            // odd step t+1 (uses bY)
            if (t + 2 < nk) { stage(buf ^ 1, t + 2); loadB(bX, t + 2); }
            __builtin_amdgcn_sched_barrier(0);
            if (t + 2 < nk) wait_vm<6>(); else wait_vm<0>();
            block_barrier();
            compute(buf, bY);
            if (t + 2 < nk) { block_barrier(); buf ^= 1; }
        }
    }

    // epilogue
    #pragma unroll
    for (int n = 0; n < NF; ++n) {
        int coll = wc * (BN / WC) + n * 16 + fr;
        int colg = bn0 + coll;
        float bv = HB ? bias[colg] : 0.f;
        #pragma unroll
        for (int m = 0; m < MF; ++m) {
            int rowl = wr * (BM / WR) + m * 16 + fq * 4;
            #pragma unroll
            for (int r = 0; r < 4; ++r) {
                size_t row = bm0 + rowl + r;
                float v = acc[m][n][r] + bv;
                if constexpr (HA) v += aux[row * (size_t)N + colg];   // f32 residual
                size_t oc = SWZO ? (size_t)swzcol(rowl + r, colg) : (size_t)colg;
                store_out(C, row * (size_t)N + oc, v);
            }
        }
    }
}

// ---------------- SSM scan (chunked, 3 passes) ----------------
__device__ __forceinline__ void ssm_params(const float* A_log, const float* log_delta,
                                           const float* Bv, int n, float& Ab, float& Bb)
{
    float A  = -expf(A_log[n]);
    float dl = log1pf(expf(log_delta[n]));   // softplus
    float dA2 = dl * A * 0.5f;
    float inv = 1.0f / (1.0f - dA2);
    Ab = (1.0f + dA2) * inv;
    Bb = dl * inv * Bv[n];
}

__global__ __launch_bounds__(64) void scan_pass1(const float* __restrict__ xs,
                                                 const float* __restrict__ A_log,
                                                 const float* __restrict__ log_delta,
                                                 const float* __restrict__ Bv,
                                                 float* __restrict__ carry)
{
    int b = blockIdx.x / NCHUNK;
    int c = blockIdx.x % NCHUNK;
    int n = threadIdx.x;
    float Ab, Bb;
    ssm_params(A_log, log_delta, Bv, n, Ab, Bb);
    size_t base = ((size_t)b * L_SEQ + (size_t)c * LCH) * DS + n;
    float h = 0.0f;
    for (int t = 0; t < LCH; ++t)
        h = Ab * h + Bb * xs[base + (size_t)t * DS];
    carry[((size_t)b * NCHUNK + c) * DS + n] = h;
}

__global__ __launch_bounds__(64) void scan_pass2(const float* __restrict__ A_log,
                                                 const float* __restrict__ log_delta,
                                                 const float* __restrict__ Bv,
                                                 const float* __restrict__ carry,
                                                 float* __restrict__ hin)
{
    int b = blockIdx.x;
    int n = threadIdx.x;
    float Ab, Bb;
    ssm_params(A_log, log_delta, Bv, n, Ab, Bb);
    float powA = powf(Ab, (float)LCH);
    float h = 0.0f;
    for (int c = 0; c < NCHUNK; ++c) {
        size_t idx = ((size_t)b * NCHUNK + c) * DS + n;
        hin[idx] = h;
        h = powA * h + carry[idx];
    }
}

// ys written PRE-SWIZZLED (A-operand of the dual GEMM, K=64)
__global__ __launch_bounds__(64) void scan_pass3(const float* __restrict__ xs,
                                                 const float* __restrict__ A_log,
                                                 const float* __restrict__ log_delta,
                                                 const float* __restrict__ Bv,
                                                 const float* __restrict__ Cv,
                                                 const float* __restrict__ hin,
                                                 ushort_t* __restrict__ ys)
{
    int b = blockIdx.x / NCHUNK;
    int c = blockIdx.x % NCHUNK;
    int n = threadIdx.x;
    float Ab, Bb;
    ssm_params(A_log, log_delta, Bv, n, Ab, Bb);
    float Cn = Cv[n];
    size_t base = ((size_t)b * L_SEQ + (size_t)c * LCH) * DS + n;
    size_t rowbase = ((size_t)b * L_SEQ + (size_t)c * LCH) * DS;
    float h = hin[((size_t)b * NCHUNK + c) * DS + n];
    for (int t = 0; t < LCH; ++t) {
        h = Ab * h + Bb * xs[base + (size_t)t * DS];
        int col = (((n >> 3) ^ (t & 7)) << 3) | (n & 7);   // row&7 == t&7
        ys[rowbase + (size_t)t * DS + col] = f2bf(Cn * h);
    }
}

// ---------------- launcher ----------------
extern "C" void kernel_launch(void* const* d_in, const int* in_sizes, int n_in,
                              void* d_out, int out_size, void* d_ws, size_t ws_size,
                              hipStream_t stream)
{
    const float* x         = (const float*)d_in[0];
    const float* ln_gamma  = (const float*)d_in[1];
    const float* ln_beta   = (const float*)d_in[2];
    const float* W_in      = (const float*)d_in[3];
    const float* b_in      = (const float*)d_in[4];
    const float* W_xs      = (const float*)d_in[5];
    const float* A_log     = (const float*)d_in[6];
    const float* log_delta = (const float*)d_in[7];
    const float* Bv        = (const float*)d_in[8];
    const float* Cv        = (const float*)d_in[9];
    const float* Dv        = (const float*)d_in[10];
    const float* W_so      = (const float*)d_in[11];
    const float* W_out     = (const float*)d_in[12];
    const float* b_out     = (const float*)d_in[13];
    float* out = (float*)d_out;

    const size_t M = M_ROWS;
    float*    xs_f     = (float*)d_ws;                         // M*64 f32
    ushort_t* xn_b     = (ushort_t*)(xs_f + M * DS);           // M*512 bf16
    ushort_t* z_b      = xn_b + M * (size_t)DM;                // M*512 bf16
    ushort_t* ys_b     = z_b + M * (size_t)DM;                 // M*64 bf16
    ushort_t* WinPk    = ys_b + M * (size_t)DS;                // 512*512
    ushort_t* WinxsPk  = WinPk + (size_t)DM * DM;              // 512*64
    ushort_t* WsooutPk = WinxsPk + (size_t)DM * DS;            // 64*512
    ushort_t* WdoutPk  = WsooutPk + (size_t)DS * DM;           // 512*512
    float*    sWsoOut  = (float*)(WdoutPk + (size_t)DM * DM);  // 64*512
    float*    sWinxs   = sWsoOut + (size_t)DS * DM;            // 512*64
    float*    sBxs     = sWinxs + (size_t)DM * DS;             // 64
    float*    carry    = sBxs + 64;                            // 8*256*64
    float*    hin      = carry + NB * NCHUNK * DS;             // 8*256*64

    // weight-product precompute + fragment packing (tiny)
    prep<<<dim3(257), dim3(256), 0, stream>>>(W_so, W_out, W_in, W_xs, b_in,
                                              sWsoOut, sWinxs, sBxs);
    pack_all<<<dim3(589824 / 256), dim3(256), 0, stream>>>(W_in, sWinxs, sWsoOut, W_out, Dv,
                                                           WinPk, WinxsPk, WsooutPk, WdoutPk);
    // LN -> xn (pre-swizzled bf16)
    ln_kernel<<<dim3((unsigned)M), dim3(64), 0, stream>>>(x, ln_gamma, ln_beta, xn_b);
    // G2: z = xn @ W_in + b_in        (bf16 pre-swizzled out)
    gemm_bp<128, 2, 4, bf16, false, true, false, true>
        <<<dim3((M / 128) * (DM / 128)), dim3(512), 0, stream>>>(nullptr, nullptr, xn_b, WinPk,
                                                                 b_in, nullptr, (bf16*)z_b,
                                                                 (int)M, DM, DM);
    // G3': xs = xn @ (W_in@W_xs) + b_in@W_xs   (f32 out, plain)
    gemm_bp<64, 4, 2, float, false, true, false, false>
        <<<dim3(M / 128), dim3(512), 0, stream>>>(nullptr, nullptr, xn_b, WinxsPk,
                                                  sBxs, nullptr, xs_f, (int)M, DS, DM);
    // scan
    scan_pass1<<<dim3(NB * NCHUNK), dim3(64), 0, stream>>>(xs_f, A_log, log_delta, Bv, carry);
    scan_pass2<<<dim3(NB), dim3(64), 0, stream>>>(A_log, log_delta, Bv, carry, hin);
    scan_pass3<<<dim3(NB * NCHUNK), dim3(64), 0, stream>>>(xs_f, A_log, log_delta, Bv, Cv, hin, ys_b);
    // GD: out = ys@(W_so@W_out) + z@(D·W_out) + b_out + x   (f32 out + residual)
    gemm_bp<128, 2, 4, float, true, true, true, false>
        <<<dim3((M / 128) * (DM / 128)), dim3(512), 0, stream>>>(ys_b, WsooutPk, z_b, WdoutPk,
                                                                 b_out, x, out, (int)M, DM, DM);
}

// Round 8
// 211.657 us; speedup vs baseline: 1.5905x; 1.2236x over previous
//
#include <hip/hip_runtime.h>
#include <hip/hip_bf16.h>
#include <cstddef>
#include <cstdint>

#define DM 512
#define DS 64
#define L_SEQ 8192
#define NB 8
#define M_ROWS (NB * L_SEQ)      // 65536
#define LN_EPS 1e-3f
#define NCHUNK 256
#define LCH 32                   // NCHUNK * LCH == L_SEQ

typedef __attribute__((ext_vector_type(8))) short short8;
typedef __attribute__((ext_vector_type(4))) float f32x4;
using bf16 = __hip_bfloat16;
using ushort_t = unsigned short;

__device__ __forceinline__ unsigned short f2bf(float f) {
    bf16 h = __float2bfloat16(f);
    return *reinterpret_cast<unsigned short*>(&h);
}

// Pre-swizzle column map for A-operands (rule #21: linear global_load_lds +
// swizzle applied at produce time + matching swizzled ds_read):
// within each 64-elem (128B) row segment, 8-elem granule g -> g ^ (row&7).
__device__ __forceinline__ int swzcol(int row, int col) {
    return (col & ~63) | (((((col >> 3) & 7) ^ (row & 7))) << 3) | (col & 7);
}

// B-operand MFMA fragment packing: element (k, n) of a KxN weight ->
// pk[((n16*Kd32 + kt)*64 + fq*16 + fr)*8 + e]; one wave fragment = 1 KB contig.
__device__ __forceinline__ size_t pkidx(int k, int n, int Kd32) {
    int n16 = n >> 4, fr = n & 15, kt = k >> 5, fq = (k >> 3) & 3, e = k & 7;
    return (((size_t)(n16 * Kd32 + kt) * 64 + fq * 16 + fr) << 3) + e;
}

__device__ __forceinline__ void gload_lds16(const void* g, void* l) {
    __builtin_amdgcn_global_load_lds(
        (const __attribute__((address_space(1))) void*)g,
        (__attribute__((address_space(3))) void*)l, 16, 0, 0);
}

template<int N> __device__ __forceinline__ void wait_vm() {
    static_assert(N == 0 || N == 6, "");
    if constexpr (N == 0) asm volatile("s_waitcnt vmcnt(0)" ::: "memory");
    else                  asm volatile("s_waitcnt vmcnt(6)" ::: "memory");
}

__device__ __forceinline__ void block_barrier() {
    asm volatile("" ::: "memory");
    __builtin_amdgcn_s_barrier();
    asm volatile("" ::: "memory");
}

// ---------------- prep: composite weight products (fp32) ----------------
// sWc2[s][j] = sum_c W_so[s][c]*W_out[c][j]            (64x512)
// sWc1[k][n] = sum_c W_in[k][c]*W_xs[c][n]             (512x64)
// bc1[n]     = sum_c b_in[c]*W_xs[c][n]                (64)
// sWc3[k][j] = sum_c W_in[k][c]*D[c]*W_out[c][j]       (512x512)
// bc2[j]     = b_out[j] + sum_c b_in[c]*D[c]*W_out[c][j]  (512)
__global__ __launch_bounds__(256) void prep(const float* __restrict__ W_so,
                                            const float* __restrict__ W_out,
                                            const float* __restrict__ W_in,
                                            const float* __restrict__ W_xs,
                                            const float* __restrict__ b_in,
                                            const float* __restrict__ b_out,
                                            const float* __restrict__ Dv,
                                            float* __restrict__ sWc2,
                                            float* __restrict__ sWc1,
                                            float* __restrict__ bc1,
                                            float* __restrict__ sWc3,
                                            float* __restrict__ bc2)
{
    int i = blockIdx.x * 256 + threadIdx.x;
    if (i < 32768) {
        int s = i >> 9, j = i & 511;
        float a = 0.f;
        for (int c = 0; c < 512; ++c) a += W_so[s * 512 + c] * W_out[c * 512 + j];
        sWc2[i] = a;
    } else if (i < 65536) {
        int idx = i - 32768; int k = idx >> 6, n = idx & 63;
        float a = 0.f;
        for (int c = 0; c < 512; ++c) a += W_in[k * 512 + c] * W_xs[c * 64 + n];
        sWc1[idx] = a;
    } else if (i < 65600) {
        int n = i - 65536;
        float a = 0.f;
        for (int c = 0; c < 512; ++c) a += b_in[c] * W_xs[c * 64 + n];
        bc1[n] = a;
    } else if (i < 327744) {
        int idx = i - 65600; int k = idx >> 9, j = idx & 511;
        float a = 0.f;
        for (int c = 0; c < 512; ++c) a += W_in[k * 512 + c] * Dv[c] * W_out[c * 512 + j];
        sWc3[idx] = a;
    } else if (i < 328256) {
        int j = i - 327744;
        float a = b_out[j];
        for (int c = 0; c < 512; ++c) a += b_in[c] * Dv[c] * W_out[c * 512 + j];
        bc2[j] = a;
    }
}

// ---------------- pack composite weights into fragment order (bf16) ----------
__global__ __launch_bounds__(256) void pack_all(const float* __restrict__ sWc3,
                                                const float* __restrict__ sWc1,
                                                const float* __restrict__ sWc2,
                                                ushort_t* __restrict__ Wc3Pk,
                                                ushort_t* __restrict__ Wc1Pk,
                                                ushort_t* __restrict__ Wc2Pk)
{
    int i = blockIdx.x * 256 + threadIdx.x;
    if (i < 262144) {                 // Wc3: K=512, N=512
        int k = i >> 9, n = i & 511;
        Wc3Pk[pkidx(k, n, 16)] = f2bf(sWc3[i]);
    } else if (i < 294912) {          // Wc1: K=512, N=64
        int j = i - 262144; int k = j >> 6, n = j & 63;
        Wc1Pk[pkidx(k, n, 16)] = f2bf(sWc1[j]);
    } else if (i < 327680) {          // Wc2: K=64, N=512 -> Kd32=2
        int j = i - 294912; int s = j >> 9, n = j & 511;
        Wc2Pk[pkidx(s, n, 2)] = f2bf(sWc2[j]);
    }
}

// ---------------- LayerNorm: one wave per row, pre-swizzled bf16 out -----------
__global__ __launch_bounds__(64) void ln_kernel(const float* __restrict__ x,
                                                const float* __restrict__ gamma,
                                                const float* __restrict__ beta,
                                                ushort_t* __restrict__ xn)
{
    size_t row = blockIdx.x;
    int lane = threadIdx.x;
    const float4* xr = (const float4*)(x + row * DM);
    float4 v0 = xr[lane * 2];
    float4 v1 = xr[lane * 2 + 1];
    float s  = v0.x + v0.y + v0.z + v0.w + v1.x + v1.y + v1.z + v1.w;
    float s2 = v0.x*v0.x + v0.y*v0.y + v0.z*v0.z + v0.w*v0.w
             + v1.x*v1.x + v1.y*v1.y + v1.z*v1.z + v1.w*v1.w;
    #pragma unroll
    for (int off = 32; off > 0; off >>= 1) {
        s  += __shfl_xor(s,  off);
        s2 += __shfl_xor(s2, off);
    }
    float mu  = s * (1.0f / DM);
    float var = s2 * (1.0f / DM) - mu * mu;
    float rs  = rsqrtf(var + LN_EPS);
    const float4* g4 = (const float4*)gamma;
    const float4* b4 = (const float4*)beta;
    float4 g0 = g4[lane * 2], g1 = g4[lane * 2 + 1];
    float4 bb0 = b4[lane * 2], bb1 = b4[lane * 2 + 1];
    short8 o;
    o[0] = (short)f2bf((v0.x - mu) * rs * g0.x + bb0.x);
    o[1] = (short)f2bf((v0.y - mu) * rs * g0.y + bb0.y);
    o[2] = (short)f2bf((v0.z - mu) * rs * g0.z + bb0.z);
    o[3] = (short)f2bf((v0.w - mu) * rs * g0.w + bb0.w);
    o[4] = (short)f2bf((v1.x - mu) * rs * g1.x + bb1.x);
    o[5] = (short)f2bf((v1.y - mu) * rs * g1.y + bb1.y);
    o[6] = (short)f2bf((v1.z - mu) * rs * g1.z + bb1.z);
    o[7] = (short)f2bf((v1.w - mu) * rs * g1.w + bb1.w);
    int g = (lane & 7) ^ ((int)row & 7);          // swizzled granule
    *(short8*)(xn + row * DM + (lane >> 3) * 64 + g * 8) = o;
}

// ---------------- epilogue helpers ----------------
__device__ __forceinline__ void store_out(float* C, size_t i, float v) { C[i] = v; }
__device__ __forceinline__ void store_out(bf16* C, size_t i, float v)  { C[i] = __float2bfloat16(v); }

// ---------------- MFMA GEMM: A via LDS (counted vmcnt dbuf), B via packed-global
// -> registers (ping-pong, 1 step ahead). Optionally dual-pair (GD kernel):
// t==0: (A1,B1,K=64), t>=1: (A2,B2,K=K2). BM=128, BK=64, 512 thr (8 waves WRxWC).
template<int BN, int WR, int WC, typename OutT, bool DUAL, bool HB, bool HA, bool SWZO>
__global__ __launch_bounds__(512, 4) void gemm_bp(const ushort_t* __restrict__ A1,
                                                  const ushort_t* __restrict__ B1,
                                                  const ushort_t* __restrict__ A2,
                                                  const ushort_t* __restrict__ B2,
                                                  const float* __restrict__ bias,
                                                  const float* __restrict__ aux,
                                                  OutT* __restrict__ C,
                                                  int M, int N, int K2)
{
    constexpr int BM = 128;
    constexpr int MF = BM / (16 * WR), NF = BN / (16 * WC);
    static_assert(NF == 2, "b ping-pong arrays assume NF==2");
    __shared__ unsigned char LDS[2][BM * 128];    // 32 KB total

    const int tid = threadIdx.x;
    const int lane = tid & 63, w = tid >> 6;
    const int fr = lane & 15, fq = lane >> 4;
    const int wr = w % WR, wc = w / WR;

    // XCD-aware bijective swizzle (T1), N-fastest (gridDim.x % 8 == 0)
    const int ny = N / BN;
    const int per = (int)gridDim.x >> 3;
    const int lg = ((int)blockIdx.x & 7) * per + ((int)blockIdx.x >> 3);
    const size_t bm0 = (size_t)(lg / ny) * BM;
    const int bn0 = (lg % ny) * BN;
    const int nk = (DUAL ? 1 : 0) + K2 / 64;

    f32x4 acc[MF][NF];
    #pragma unroll
    for (int m = 0; m < MF; ++m)
        #pragma unroll
        for (int n = 0; n < NF; ++n)
            acc[m][n] = (f32x4){0.f, 0.f, 0.f, 0.f};

    auto stage = [&](int buf, int t) {
        #pragma unroll
        for (int j = 0; j < 2; ++j) {
            int r = j * 64 + (tid >> 3);
            const ushort_t* src;
            if constexpr (DUAL) {
                if (t == 0) src = A1 + (bm0 + r) * (size_t)64 + (tid & 7) * 8;
                else        src = A2 + (bm0 + r) * (size_t)512 + (size_t)(t - 1) * 64 + (tid & 7) * 8;
            } else {
                src = A2 + (bm0 + r) * (size_t)K2 + (size_t)t * 64 + (tid & 7) * 8;
            }
            gload_lds16(src, &LDS[buf][j * 8192 + w * 1024]);
        }
    };

    auto loadB = [&](short8 (&bb)[2][2], int t) {
        #pragma unroll
        for (int h = 0; h < 2; ++h)
            #pragma unroll
            for (int n = 0; n < NF; ++n) {
                int n16g = (bn0 + wc * (BN / WC) + n * 16) >> 4;
                const ushort_t* p;
                if constexpr (DUAL) {
                    if (t == 0) p = B1 + (((size_t)(n16g * 2 + h) * 64 + lane) << 3);
                    else        p = B2 + (((size_t)(n16g * 16 + (t - 1) * 2 + h) * 64 + lane) << 3);
                } else {
                    p = B2 + (((size_t)(n16g * (K2 / 32) + t * 2 + h) * 64 + lane) << 3);
                }
                bb[h][n] = *(const short8*)p;
            }
    };

    auto compute = [&](int buf, const short8 (&bb)[2][2]) {
        #pragma unroll
        for (int h = 0; h < 2; ++h) {
            short8 af[MF];
            #pragma unroll
            for (int m = 0; m < MF; ++m) {
                int row = wr * (BM / WR) + m * 16 + fr;
                int g = (h * 4 + fq) ^ (row & 7);
                af[m] = *(const short8*)&LDS[buf][row * 128 + g * 16];
            }
            #pragma unroll
            for (int m = 0; m < MF; ++m)
                #pragma unroll
                for (int n = 0; n < NF; ++n)
                    acc[m][n] = __builtin_amdgcn_mfma_f32_16x16x32_bf16(af[m], bb[h][n], acc[m][n], 0, 0, 0);
        }
    };

    short8 bX[2][2], bY[2][2];
    stage(0, 0);
    loadB(bX, 0);
    int buf = 0;
    for (int t = 0; t < nk; t += 2) {
        // even step t (uses bX)
        if (t + 1 < nk) { stage(buf ^ 1, t + 1); loadB(bY, t + 1); }
        __builtin_amdgcn_sched_barrier(0);
        if (t + 1 < nk) wait_vm<6>(); else wait_vm<0>();
        block_barrier();
        compute(buf, bX);
        if (t + 1 < nk) {
            block_barrier();
            buf ^= 1;
            // odd step t+1 (uses bY)
            if (t + 2 < nk) { stage(buf ^ 1, t + 2); loadB(bX, t + 2); }
            __builtin_amdgcn_sched_barrier(0);
            if (t + 2 < nk) wait_vm<6>(); else wait_vm<0>();
            block_barrier();
            compute(buf, bY);
            if (t + 2 < nk) { block_barrier(); buf ^= 1; }
        }
    }

    // epilogue
    #pragma unroll
    for (int n = 0; n < NF; ++n) {
        int coll = wc * (BN / WC) + n * 16 + fr;
        int colg = bn0 + coll;
        float bv = HB ? bias[colg] : 0.f;
        #pragma unroll
        for (int m = 0; m < MF; ++m) {
            int rowl = wr * (BM / WR) + m * 16 + fq * 4;
            #pragma unroll
            for (int r = 0; r < 4; ++r) {
                size_t row = bm0 + rowl + r;
                float v = acc[m][n][r] + bv;
                if constexpr (HA) v += aux[row * (size_t)N + colg];   // f32 residual
                size_t oc = SWZO ? (size_t)swzcol(rowl + r, colg) : (size_t)colg;
                store_out(C, row * (size_t)N + oc, v);
            }
        }
    }
}

// ---------------- SSM scan (chunked, 3 passes) ----------------
__device__ __forceinline__ void ssm_params(const float* A_log, const float* log_delta,
                                           const float* Bv, int n, float& Ab, float& Bb)
{
    float A  = -expf(A_log[n]);
    float dl = log1pf(expf(log_delta[n]));   // softplus
    float dA2 = dl * A * 0.5f;
    float inv = 1.0f / (1.0f - dA2);
    Ab = (1.0f + dA2) * inv;
    Bb = dl * inv * Bv[n];
}

__global__ __launch_bounds__(64) void scan_pass1(const float* __restrict__ xs,
                                                 const float* __restrict__ A_log,
                                                 const float* __restrict__ log_delta,
                                                 const float* __restrict__ Bv,
                                                 float* __restrict__ carry)
{
    int b = blockIdx.x / NCHUNK;
    int c = blockIdx.x % NCHUNK;
    int n = threadIdx.x;
    float Ab, Bb;
    ssm_params(A_log, log_delta, Bv, n, Ab, Bb);
    size_t base = ((size_t)b * L_SEQ + (size_t)c * LCH) * DS + n;
    float h = 0.0f;
    for (int t = 0; t < LCH; ++t)
        h = Ab * h + Bb * xs[base + (size_t)t * DS];
    carry[((size_t)b * NCHUNK + c) * DS + n] = h;
}

__global__ __launch_bounds__(64) void scan_pass2(const float* __restrict__ A_log,
                                                 const float* __restrict__ log_delta,
                                                 const float* __restrict__ Bv,
                                                 const float* __restrict__ carry,
                                                 float* __restrict__ hin)
{
    int b = blockIdx.x;
    int n = threadIdx.x;
    float Ab, Bb;
    ssm_params(A_log, log_delta, Bv, n, Ab, Bb);
    float powA = powf(Ab, (float)LCH);
    float h = 0.0f;
    for (int c = 0; c < NCHUNK; ++c) {
        size_t idx = ((size_t)b * NCHUNK + c) * DS + n;
        hin[idx] = h;
        h = powA * h + carry[idx];
    }
}

// ys written PRE-SWIZZLED (A-operand of the dual GEMM, K=64)
__global__ __launch_bounds__(64) void scan_pass3(const float* __restrict__ xs,
                                                 const float* __restrict__ A_log,
                                                 const float* __restrict__ log_delta,
                                                 const float* __restrict__ Bv,
                                                 const float* __restrict__ Cv,
                                                 const float* __restrict__ hin,
                                                 ushort_t* __restrict__ ys)
{
    int b = blockIdx.x / NCHUNK;
    int c = blockIdx.x % NCHUNK;
    int n = threadIdx.x;
    float Ab, Bb;
    ssm_params(A_log, log_delta, Bv, n, Ab, Bb);
    float Cn = Cv[n];
    size_t base = ((size_t)b * L_SEQ + (size_t)c * LCH) * DS + n;
    size_t rowbase = ((size_t)b * L_SEQ + (size_t)c * LCH) * DS;
    float h = hin[((size_t)b * NCHUNK + c) * DS + n];
    for (int t = 0; t < LCH; ++t) {
        h = Ab * h + Bb * xs[base + (size_t)t * DS];
        int col = (((n >> 3) ^ (t & 7)) << 3) | (n & 7);   // row&7 == t&7
        ys[rowbase + (size_t)t * DS + col] = f2bf(Cn * h);
    }
}

// ---------------- launcher ----------------
extern "C" void kernel_launch(void* const* d_in, const int* in_sizes, int n_in,
                              void* d_out, int out_size, void* d_ws, size_t ws_size,
                              hipStream_t stream)
{
    const float* x         = (const float*)d_in[0];
    const float* ln_gamma  = (const float*)d_in[1];
    const float* ln_beta   = (const float*)d_in[2];
    const float* W_in      = (const float*)d_in[3];
    const float* b_in      = (const float*)d_in[4];
    const float* W_xs      = (const float*)d_in[5];
    const float* A_log     = (const float*)d_in[6];
    const float* log_delta = (const float*)d_in[7];
    const float* Bv        = (const float*)d_in[8];
    const float* Cv        = (const float*)d_in[9];
    const float* Dv        = (const float*)d_in[10];
    const float* W_so      = (const float*)d_in[11];
    const float* W_out     = (const float*)d_in[12];
    const float* b_out     = (const float*)d_in[13];
    float* out = (float*)d_out;

    const size_t M = M_ROWS;
    float*    xs_f   = (float*)d_ws;                         // M*64 f32
    ushort_t* xn_b   = (ushort_t*)(xs_f + M * DS);           // M*512 bf16
    ushort_t* ys_b   = xn_b + M * (size_t)DM;                // M*64 bf16
    ushort_t* Wc3Pk  = ys_b + M * (size_t)DS;                // 512*512
    ushort_t* Wc1Pk  = Wc3Pk + (size_t)DM * DM;              // 512*64
    ushort_t* Wc2Pk  = Wc1Pk + (size_t)DM * DS;              // 64*512
    float*    sWc2   = (float*)(Wc2Pk + (size_t)DS * DM);    // 64*512
    float*    sWc1   = sWc2 + (size_t)DS * DM;               // 512*64
    float*    bc1    = sWc1 + (size_t)DM * DS;               // 64
    float*    sWc3   = bc1 + 64;                             // 512*512
    float*    bc2    = sWc3 + (size_t)DM * DM;               // 512
    float*    carry  = bc2 + DM;                             // 8*256*64
    float*    hin    = carry + NB * NCHUNK * DS;             // 8*256*64

    // composite weight precompute + fragment packing (tiny, L2-resident)
    prep<<<dim3(1283), dim3(256), 0, stream>>>(W_so, W_out, W_in, W_xs, b_in, b_out, Dv,
                                               sWc2, sWc1, bc1, sWc3, bc2);
    pack_all<<<dim3(1280), dim3(256), 0, stream>>>(sWc3, sWc1, sWc2, Wc3Pk, Wc1Pk, Wc2Pk);
    // LN -> xn (pre-swizzled bf16)
    ln_kernel<<<dim3((unsigned)M), dim3(64), 0, stream>>>(x, ln_gamma, ln_beta, xn_b);
    // G3': xs = xn @ Wc1 + bc1   (f32 out, plain)
    gemm_bp<64, 4, 2, float, false, true, false, false>
        <<<dim3(M / 128), dim3(512), 0, stream>>>(nullptr, nullptr, xn_b, Wc1Pk,
                                                  bc1, nullptr, xs_f, (int)M, DS, DM);
    // scan
    scan_pass1<<<dim3(NB * NCHUNK), dim3(64), 0, stream>>>(xs_f, A_log, log_delta, Bv, carry);
    scan_pass2<<<dim3(NB), dim3(64), 0, stream>>>(A_log, log_delta, Bv, carry, hin);
    scan_pass3<<<dim3(NB * NCHUNK), dim3(64), 0, stream>>>(xs_f, A_log, log_delta, Bv, Cv, hin, ys_b);
    // GD': out = ys@Wc2 + xn@Wc3 + bc2 + x   (f32 out + residual; z eliminated)
    gemm_bp<128, 2, 4, float, true, true, true, false>
        <<<dim3((M / 128) * (DM / 128)), dim3(512), 0, stream>>>(ys_b, Wc2Pk, xn_b, Wc3Pk,
                                                                 bc2, x, out, (int)M, DM, DM);
}